// Round 3
// baseline (382.734 us; speedup 1.0000x reference)
//
#include <hip/hip_runtime.h>
#include <math.h>

#define N_NODES 50000
#define N_EDGES 500000
#define DIM 64
#define NUM_RELS 16
#define GPB 160   // 16*GPB = 2560 blocks for k5

// ---------------- ws layout (4-byte units) ----------------
// [192,208)        counts[16]
// [228,244)        cursor[16]
// [256, +N)        sn[N]
// [50256, +N)      dn[N]
// [100256, +E)     ae[E]
// [600256, +E)     perm[E]

// K1: per-node score scalars + zero output + zero counters.
// uvecs (u_s,u_d) computed redundantly per block into LDS (cheap, kills k0).
__global__ void k1_node(const float* __restrict__ h,
                        const float* __restrict__ W_shared,
                        const float* __restrict__ W_attn,
                        float* __restrict__ sn, float* __restrict__ dn,
                        float4* __restrict__ out4,
                        int* __restrict__ counts, int* __restrict__ cursor) {
    __shared__ float sus[64], sud[64];
    int t = threadIdx.x;
    if (t < 64) {
        float us = 0.f, ud = 0.f;
        for (int o = 0; o < 64; ++o) {
            float w = W_shared[o * 64 + t];
            us = fmaf(w, W_attn[o],       us);
            ud = fmaf(w, W_attn[128 + o], ud);
        }
        sus[t] = us; sud[t] = ud;
    }
    // redundant zeroing from every block (identical values, pre-k2: benign)
    if (t >= 64 && t < 80)  counts[t - 64] = 0;
    if (t >= 80 && t < 96)  cursor[t - 80] = 0;
    __syncthreads();

    int n = blockIdx.x * blockDim.x + t;
    if (n >= N_NODES) return;
    const float* hp = h + (size_t)n * DIM;
    float s = 0.f, d = 0.f;
#pragma unroll
    for (int i = 0; i < 64; i += 4) {
        float4 v = *(const float4*)(hp + i);
        s = fmaf(v.x, sus[i], s);     s = fmaf(v.y, sus[i + 1], s);
        s = fmaf(v.z, sus[i + 2], s); s = fmaf(v.w, sus[i + 3], s);
        d = fmaf(v.x, sud[i], d);     d = fmaf(v.y, sud[i + 1], d);
        d = fmaf(v.z, sud[i + 2], d); d = fmaf(v.w, sud[i + 3], d);
    }
    sn[n] = s; dn[n] = d;
    float4 z = make_float4(0.f, 0.f, 0.f, 0.f);
#pragma unroll
    for (int i = 0; i < 16; ++i) out4[(size_t)n * 16 + i] = z;
}

// K2: ae[e] = sn[src]+dn[dst]+he[e]·v_e, plus per-relation histogram.
// v_e computed redundantly per block into LDS.
__global__ void k2_ae(const float4* __restrict__ he4,
                      const int* __restrict__ src, const int* __restrict__ dst,
                      const int* __restrict__ rel,
                      const float* __restrict__ W_shared,
                      const float* __restrict__ W_attn,
                      const float* __restrict__ sn, const float* __restrict__ dn,
                      float* __restrict__ ae, int* __restrict__ counts) {
    __shared__ float sve[64];
    __shared__ int hist[NUM_RELS];
    int t = threadIdx.x;
    if (t < NUM_RELS) hist[t] = 0;
    if (t < 64) {
        float ve = 0.f;
        for (int o = 0; o < 64; ++o)
            ve = fmaf(W_shared[o * 64 + t], W_attn[64 + o], ve);
        sve[t] = ve;
    }
    __syncthreads();

    const int lane = t & 63;
    const int sub  = lane & 3;
    const int eo   = lane >> 2;
    const int gw   = blockIdx.x * 4 + (t >> 6);
    const int nw   = gridDim.x * 4;

    float4 u0 = *(const float4*)(sve + sub * 16 + 0);
    float4 u1 = *(const float4*)(sve + sub * 16 + 4);
    float4 u2 = *(const float4*)(sve + sub * 16 + 8);
    float4 u3 = *(const float4*)(sve + sub * 16 + 12);

    for (int base = gw * 16; base < N_EDGES; base += nw * 16) {
        int e = base + eo;
        float p = 0.f;
        if (e < N_EDGES) {
            const float4* row = he4 + (size_t)e * 16 + sub * 4;
            float4 a = row[0], b = row[1], c = row[2], d = row[3];
            p = a.x*u0.x + a.y*u0.y + a.z*u0.z + a.w*u0.w
              + b.x*u1.x + b.y*u1.y + b.z*u1.z + b.w*u1.w
              + c.x*u2.x + c.y*u2.y + c.z*u2.z + c.w*u2.w
              + d.x*u3.x + d.y*u3.y + d.z*u3.z + d.w*u3.w;
        }
        p += __shfl_xor(p, 1, 64);
        p += __shfl_xor(p, 2, 64);
        if (sub == 0 && e < N_EDGES) {
            ae[e] = p + sn[src[e]] + dn[dst[e]];
            atomicAdd(&hist[rel[e]], 1);
        }
    }
    __syncthreads();
    if (t < NUM_RELS && hist[t]) atomicAdd(&counts[t], hist[t]);
}

// K4: bucket edge ids by relation; offs scanned locally from counts (kills k3).
__global__ void k4_scatter(const int* __restrict__ rel,
                           const int* __restrict__ counts,
                           int* __restrict__ cursor,
                           int* __restrict__ perm) {
    __shared__ int hist[NUM_RELS];
    __shared__ int bbase[NUM_RELS];
    __shared__ int soffs[NUM_RELS];
    int t = threadIdx.x;
    if (t < NUM_RELS) hist[t] = 0;
    if (t == 0) {
        int acc = 0;
        for (int j = 0; j < NUM_RELS; ++j) { soffs[j] = acc; acc += counts[j]; }
    }
    __syncthreads();
    int e = blockIdx.x * 1024 + t;
    int r = 0, lpos = 0;
    bool valid = (e < N_EDGES);
    if (valid) { r = rel[e]; lpos = atomicAdd(&hist[r], 1); }
    __syncthreads();
    if (t < NUM_RELS) bbase[t] = hist[t] ? atomicAdd(&cursor[t], hist[t]) : 0;
    __syncthreads();
    if (valid) perm[soffs[r] + bbase[r] + lpos] = e;
}

// K5: main. One wave = one relation; lane o holds W_rel[r][:,o] pinned in
// 64 VGPRs. 64-edge batches; 2-edge unroll -> two s_load streams in flight
// per lgkmcnt drain; native fp32 atomics out.
__global__ __launch_bounds__(256, 4) void k5_main(
    const float* __restrict__ h,
    const int* __restrict__ src, const int* __restrict__ dst,
    const float* __restrict__ W_rel,
    const float* __restrict__ ae,
    const int* __restrict__ counts, const int* __restrict__ perm,
    float* __restrict__ out)
{
    const int lane = threadIdx.x & 63;
    const int wib  = __builtin_amdgcn_readfirstlane(threadIdx.x >> 6);
    const int r    = blockIdx.x & 15;
    const int g    = blockIdx.x >> 4;
    const int wr   = g * 4 + wib;
    const int WPR  = GPB * 4;

    // local exclusive scan of counts -> [begin,end) for relation r
    int begin = 0, cr = 0;
#pragma unroll
    for (int j = 0; j < NUM_RELS; ++j) {
        int c = counts[j];
        if (j < r) begin += c;
        if (j == r) cr = c;
    }
    const int end = begin + cr;

    // lane's column of W_rel[r], pinned in VGPRs
    float w[64];
    const float* wb = W_rel + (size_t)r * (DIM * DIM) + lane;
#pragma unroll
    for (int i = 0; i < 64; ++i) w[i] = wb[i * 64];
#pragma unroll
    for (int i = 0; i < 64; ++i) asm volatile("" : "+v"(w[i]));

    for (int base = begin + wr * 64; base < end; base += WPR * 64) {
        int s_l = 0, d_l = 0; float a_l = 0.f;
        if (base + lane < end) {
            int e_l = perm[base + lane];
            s_l = src[e_l];
            d_l = dst[e_l];
            a_l = ae[e_l];
        }
        const int kmax = min(64, end - base);
        int k = 0;
        for (; k + 2 <= kmax; k += 2) {
            const int si0 = __builtin_amdgcn_readlane(s_l, k);
            const int si1 = __builtin_amdgcn_readlane(s_l, k + 1);
            const int di0 = __builtin_amdgcn_readlane(d_l, k);
            const int di1 = __builtin_amdgcn_readlane(d_l, k + 1);
            const float a0 = __int_as_float(__builtin_amdgcn_readlane(__float_as_int(a_l), k));
            const float a1 = __int_as_float(__builtin_amdgcn_readlane(__float_as_int(a_l), k + 1));
            const float* hp0 = h + (size_t)si0 * DIM;
            const float* hp1 = h + (size_t)si1 * DIM;
            float x0 = 0.f, y0 = 0.f, x1 = 0.f, y1 = 0.f;
#pragma unroll
            for (int i = 0; i < 64; i += 2) {
                x0 = fmaf(hp0[i],     w[i],     x0);
                x1 = fmaf(hp1[i],     w[i],     x1);
                y0 = fmaf(hp0[i + 1], w[i + 1], y0);
                y1 = fmaf(hp1[i + 1], w[i + 1], y1);
            }
            unsafeAtomicAdd(out + (size_t)di0 * DIM + lane, a0 * (x0 + y0));
            unsafeAtomicAdd(out + (size_t)di1 * DIM + lane, a1 * (x1 + y1));
        }
        if (k < kmax) {
            const int si = __builtin_amdgcn_readlane(s_l, k);
            const int di = __builtin_amdgcn_readlane(d_l, k);
            const float ak = __int_as_float(__builtin_amdgcn_readlane(__float_as_int(a_l), k));
            const float* hp = h + (size_t)si * DIM;
            float x = 0.f, y = 0.f;
#pragma unroll
            for (int i = 0; i < 64; i += 2) {
                x = fmaf(hp[i],     w[i],     x);
                y = fmaf(hp[i + 1], w[i + 1], y);
            }
            unsafeAtomicAdd(out + (size_t)di * DIM + lane, ak * (x + y));
        }
    }
}

// K6: relu in place
__global__ void k6_relu(float4* __restrict__ out, int n4) {
    int i = blockIdx.x * blockDim.x + threadIdx.x;
    if (i < n4) {
        float4 v = out[i];
        v.x = fmaxf(v.x, 0.f); v.y = fmaxf(v.y, 0.f);
        v.z = fmaxf(v.z, 0.f); v.w = fmaxf(v.w, 0.f);
        out[i] = v;
    }
}

extern "C" void kernel_launch(void* const* d_in, const int* in_sizes, int n_in,
                              void* d_out, int out_size, void* d_ws, size_t ws_size,
                              hipStream_t stream) {
    const float* h        = (const float*)d_in[0];
    const float* he       = (const float*)d_in[1];
    const int*   src      = (const int*)d_in[2];
    const int*   dst      = (const int*)d_in[3];
    const int*   rel      = (const int*)d_in[4];
    const float* W_shared = (const float*)d_in[5];
    const float* W_attn   = (const float*)d_in[6];
    const float* W_rel    = (const float*)d_in[7];
    float*       out      = (float*)d_out;

    int*   counts = (int*)d_ws + 192;
    int*   cursor = (int*)d_ws + 228;
    float* sn     = (float*)d_ws + 256;
    float* dn     = (float*)d_ws + 50256;
    float* ae     = (float*)d_ws + 100256;
    int*   perm   = (int*)d_ws + 600256;

    k1_node<<<(N_NODES + 255) / 256, 256, 0, stream>>>(h, W_shared, W_attn, sn, dn,
                                                       (float4*)out, counts, cursor);
    k2_ae<<<1024, 256, 0, stream>>>((const float4*)he, src, dst, rel, W_shared, W_attn,
                                    sn, dn, ae, counts);
    k4_scatter<<<(N_EDGES + 1023) / 1024, 1024, 0, stream>>>(rel, counts, cursor, perm);
    k5_main<<<NUM_RELS * GPB, 256, 0, stream>>>(h, src, dst, W_rel, ae, counts, perm, out);
    int n4 = out_size / 4;
    k6_relu<<<(n4 + 255) / 256, 256, 0, stream>>>((float4*)out, n4);
}